// Round 7
// baseline (163.023 us; speedup 1.0000x reference)
//
#include <hip/hip_runtime.h>
#include <hip/hip_bf16.h>

// ---------------------------------------------------------------------------
// GraphAttentionLayer: scores = (x*w_map) @ x^T ; attn = softmax(scores);
// agg = attn @ x ; out = agg@w_att^T + x@w_res^T ; BN(train) ; SELU.
// B=8, N=2048, D=256. All-bf16 MFMA pipeline. No-max softmax (|s| <~ 4).
// R7: tail optimization (k1 frozen at the R6 structure, 64 us):
//  - k2: global_load_lds double-buffered staging, 1 barrier/iter, source-side
//    XOR chunk swizzle (c ^ row&7) -> unpadded stride-64 tiles, 2-way reads.
//  - k0_wc folded into k0_prep (blocks 256..319).
//  - k4: per-channel scale/shift precomputed in LDS (no per-elem rsqrt).
// ---------------------------------------------------------------------------

typedef __attribute__((ext_vector_type(8))) short  bf16x8;   // 8 bf16 = 4 VGPRs
typedef __attribute__((ext_vector_type(4))) float  f32x4;

#define MFMA16(a, b, c) __builtin_amdgcn_mfma_f32_16x16x32_bf16((a), (b), (c), 0, 0, 0)

constexpr int   NB = 8, NN = 2048, ND = 256;
constexpr int   ROWS = NB * NN;                 // 16384
constexpr float BN_EPS = 1e-5f;
constexpr float SELU_ALPHA = 1.6732632423543772f;
constexpr float SELU_SCALE = 1.0507009873554805f;

__device__ __forceinline__ unsigned short f2bf(float f) {
  union { float f; unsigned int u; } v; v.f = f;
  unsigned int u = v.u;
  u += 0x7FFFu + ((u >> 16) & 1u);              // round-to-nearest-even
  return (unsigned short)(u >> 16);
}
__device__ __forceinline__ float bf2f(unsigned short h) {
  union { float f; unsigned int u; } v; v.u = ((unsigned int)h) << 16;
  return v.f;
}

// async 16B/lane global->LDS; LDS dest is wave-uniform base + lane*16.
__device__ __forceinline__ void async_copy16(const unsigned short* g, unsigned short* l) {
  __builtin_amdgcn_global_load_lds(
      (const __attribute__((address_space(1))) void*)g,
      (__attribute__((address_space(3))) void*)l, 16, 0, 0);
}

// ---------------------------------------------------------------------------
// k0: blocks 0..255: x (fp32) -> bf16 into AX right half AND Xt (d-major).
//     blocks 256..319: WC[c][0:256]=w_att[c], WC[c][256:512]=w_res[c];
//     block 256 also zeroes the BN-stats accumulator.
// ---------------------------------------------------------------------------
__global__ __launch_bounds__(256) void k0_prep(const float* __restrict__ x,
                                               const float* __restrict__ w_att,
                                               const float* __restrict__ w_res,
                                               unsigned short* __restrict__ AX,
                                               unsigned short* __restrict__ Xt,
                                               unsigned short* __restrict__ WC,
                                               float* __restrict__ sums) {
  __shared__ unsigned short Ls[64 * 264];
  const int t = threadIdx.x;
  if (blockIdx.x >= 256) {                      // ---- weight-concat path ----
    const int bid = blockIdx.x - 256;
    if (bid == 0 && t < 128)
      ((float4*)sums)[t] = make_float4(0.f, 0.f, 0.f, 0.f);
    int f = (bid * 256 + t) * 8;                // < 131072
    int c = f >> 9, k = f & 511;
    const float* src = (k < 256) ? (w_att + c * 256 + k) : (w_res + c * 256 + (k - 256));
    float4 a = *(const float4*)src;
    float4 b = *(const float4*)(src + 4);
    union { unsigned short s[8]; uint4 v; } o;
    o.s[0] = f2bf(a.x); o.s[1] = f2bf(a.y); o.s[2] = f2bf(a.z); o.s[3] = f2bf(a.w);
    o.s[4] = f2bf(b.x); o.s[5] = f2bf(b.y); o.s[6] = f2bf(b.z); o.s[7] = f2bf(b.w);
    *(uint4*)(WC + f) = o.v;
    return;
  }
  const int b = blockIdx.x & 7, rt = blockIdx.x >> 3;
  const int grb = b * NN + rt * 64;             // global row base
  const int c = (t & 31) * 8, r0 = t >> 5;
#pragma unroll
  for (int q = 0; q < 8; ++q) {
    int r = r0 + q * 8;                         // 64 rows
    const float* xp = x + (size_t)(grb + r) * 256 + c;
    float4 a = *(const float4*)xp;
    float4 d = *(const float4*)(xp + 4);
    union { unsigned short s[8]; uint4 v; } xb;
    xb.s[0] = f2bf(a.x); xb.s[1] = f2bf(a.y); xb.s[2] = f2bf(a.z); xb.s[3] = f2bf(a.w);
    xb.s[4] = f2bf(d.x); xb.s[5] = f2bf(d.y); xb.s[6] = f2bf(d.z); xb.s[7] = f2bf(d.w);
    *(uint4*)(AX + (size_t)(grb + r) * 512 + 256 + c) = xb.v;
    *(uint4*)&Ls[r * 264 + c] = xb.v;
  }
  __syncthreads();
  unsigned short* dst = Xt + ((size_t)b * 256 + t) * 2048 + rt * 64;
#pragma unroll
  for (int k = 0; k < 8; ++k) {
    union { unsigned short s[8]; uint4 v; } o;
#pragma unroll
    for (int j = 0; j < 8; ++j) o.s[j] = Ls[(k * 8 + j) * 264 + t];
    *(uint4*)(dst + k * 8) = o.v;
  }
}

// ---------------------------------------------------------------------------
// k1: flash attention (R6 structure, unchanged). Block = (batch b, 64 rows),
// grid 256, 512 threads; 2 wave-groups split the j-range, 2 waves/SIMD.
// ---------------------------------------------------------------------------
__global__ __launch_bounds__(512, 2) void k1_attn(const float* __restrict__ w_map,
                                                  const unsigned short* AX,
                                                  const unsigned short* __restrict__ Xt,
                                                  unsigned short* AXw) {
  __shared__ unsigned short Ks[2][2][32 * 256];   // [group][buf] 16 KB each
  __shared__ unsigned short Vt[2][2][256 * 32];   // [group][buf] 16 KB each
  __shared__ unsigned short Psw[8][16 * 40];      // per-wave P scratch

  const int t = threadIdx.x;
  const int w = t >> 6, lane = t & 63, l15 = lane & 15, quad = lane >> 4;
  const int g = w >> 2, wg = w & 3;
  const int b = blockIdx.x & 7, it = blockIdx.x >> 3;
  const int gib = b * NN + it * 64;
  const unsigned short* Xtb = Xt + (size_t)b * 256 * 2048;
  const unsigned short* AXr = AX + (size_t)b * NN * 512 + 256;  // + row*512
  const int jgbase = g * 1024;                    // group's j range base

  int ksOff[4], vtOff[4];
#pragma unroll
  for (int q = 0; q < 4; ++q) {
    int j = wg * 8 + q * 2 + (lane >> 5);
    int ck = (lane & 31) ^ (j & 7);               // K chunk swizzle
    ksOff[q] = j * 512 + ck * 8;
    int d = wg * 64 + q * 16 + (lane >> 2);
    int cv = (lane & 3) ^ ((d >> 1) & 3);         // V chunk swizzle
    vtOff[q] = d * 2048 + cv * 8;
  }
  const int ldsOff = wg * 2048 + lane * 8;        // ushort units, per buffer

  bf16x8 qf[8];
  {
    const unsigned short* xrow = AXr + (size_t)(it * 64 + wg * 16 + l15) * 512;
#pragma unroll
    for (int kc = 0; kc < 8; ++kc) {
      bf16x8 xb = *(const bf16x8*)(xrow + kc * 32 + quad * 8);
      const float* wp = w_map + kc * 32 + quad * 8;
      float4 w0 = *(const float4*)wp, w1 = *(const float4*)(wp + 4);
      float wv[8] = {w0.x, w0.y, w0.z, w0.w, w1.x, w1.y, w1.z, w1.w};
      bf16x8 q;
#pragma unroll
      for (int i = 0; i < 8; ++i)
        q[i] = (short)f2bf(bf2f((unsigned short)xb[i]) * wv[i]);
      qf[kc] = q;
    }
  }

  const f32x4 fz = {0.f, 0.f, 0.f, 0.f};
  f32x4 oacc[16];
#pragma unroll
  for (int i = 0; i < 16; ++i) oacc[i] = fz;
  f32x4 oL = fz;

  bf16x8 onesFrag;
  {
    short o1 = (l15 == 0) ? (short)0x3F80 : (short)0;    // bf16 1.0, col 0
#pragma unroll
    for (int i = 0; i < 8; ++i) onesFrag[i] = o1;
  }

#pragma unroll
  for (int q = 0; q < 4; ++q)
    async_copy16(AXr + (size_t)jgbase * 512 + ksOff[q], &Ks[g][0][ldsOff + q * 512]);
#pragma unroll
  for (int q = 0; q < 4; ++q)
    async_copy16(Xtb + jgbase + vtOff[q], &Vt[g][0][ldsOff + q * 512]);

  for (int jt = 0; jt < 32; ++jt) {
    const int cur = jt & 1;
    __syncthreads();            // buf[cur] landed; prev-iter buf[cur^1] reads done
    if (jt < 31) {              // prefetch jt+1, drains at NEXT barrier
      const int jb1 = jgbase + (jt + 1) * 32;
#pragma unroll
      for (int q = 0; q < 4; ++q)
        async_copy16(AXr + (size_t)jb1 * 512 + ksOff[q], &Ks[g][cur ^ 1][ldsOff + q * 512]);
#pragma unroll
      for (int q = 0; q < 4; ++q)
        async_copy16(Xtb + jb1 + vtOff[q], &Vt[g][cur ^ 1][ldsOff + q * 512]);
    }
    // ---- S^T = K Q^T, two m-tiles (j = jm*16 + l15); exp -> Psw ----
#pragma unroll
    for (int jm = 0; jm < 2; ++jm) {
      const int j = jm * 16 + l15;
      f32x4 s = fz;
#pragma unroll
      for (int kc = 0; kc < 8; ++kc) {
        int ckk = kc * 4 + quad;
        bf16x8 kf = *(const bf16x8*)&Ks[g][cur][j * 256 + ((ckk ^ (j & 7)) * 8)];
        s = MFMA16(kf, qf[kc], s);
      }
      ushort4 pk;
      pk.x = f2bf(__expf(s[0])); pk.y = f2bf(__expf(s[1]));
      pk.z = f2bf(__expf(s[2])); pk.w = f2bf(__expf(s[3]));
      *(ushort4*)&Psw[w][l15 * 40 + jm * 16 + quad * 4] = pk;   // ds_write_b64
    }
    // ---- PV: A-frag from wave-private scratch (lgkm-ordered, no barrier) --
    bf16x8 af = *(const bf16x8*)&Psw[w][l15 * 40 + quad * 8];
#pragma unroll
    for (int nti = 0; nti < 16; ++nti) {
      const int d = nti * 16 + l15;
      bf16x8 vf = *(const bf16x8*)&Vt[g][cur][d * 32 + ((quad ^ ((d >> 1) & 3)) * 8)];
      oacc[nti] = MFMA16(af, vf, oacc[nti]);
    }
    oL = MFMA16(af, onesFrag, oL);
  }

  // ---- combine the two groups' partial O and L through dead LDS ----
  __syncthreads();
  float* Obuf = (float*)&Ks[0][0][0];              // 64 KB: [wg][16][256] words
  float* Lb   = (float*)&Vt[0][0][0];              // [wg][16]
  if (g == 1) {
#pragma unroll
    for (int nti = 0; nti < 16; ++nti)
#pragma unroll
      for (int r = 0; r < 4; ++r) {
        int row = quad * 4 + r;
        Obuf[wg * 4096 + row * 256 + (((nti + quad) & 15) << 4) + l15] = oacc[nti][r];
      }
    if (l15 == 0) {
#pragma unroll
      for (int r = 0; r < 4; ++r) Lb[wg * 16 + quad * 4 + r] = oL[r];
    }
  }
  __syncthreads();
  if (g == 0) {
    float ls[4];
#pragma unroll
    for (int r = 0; r < 4; ++r) ls[r] = Lb[wg * 16 + quad * 4 + r];
#pragma unroll
    for (int nti = 0; nti < 16; ++nti)
#pragma unroll
      for (int r = 0; r < 4; ++r) {
        int row = quad * 4 + r;
        oacc[nti][r] += Obuf[wg * 4096 + row * 256 + (((nti + quad) & 15) << 4) + l15];
      }
    float li[4];
#pragma unroll
    for (int r = 0; r < 4; ++r)
      li[r] = 1.0f / (__shfl(oL[r], lane & 48) + ls[r]);
#pragma unroll
    for (int nti = 0; nti < 16; ++nti) {
      const int gcol = nti * 16 + l15;
#pragma unroll
      for (int r = 0; r < 4; ++r) {
        const int grow = gib + wg * 16 + quad * 4 + r;
        AXw[(size_t)grow * 512 + gcol] = f2bf(oacc[nti][r] * li[r]);
      }
    }
  }
}

// ---------------------------------------------------------------------------
// k2: out_pre = AX @ WC^T  (M=16384, N=256, K=512). Block tile 128x64, BK=64,
// grid 512, 2 blocks/CU. R7: global_load_lds double-buffered staging,
// 1 barrier/iter; unpadded stride-64 LDS with source-side chunk swizzle
// c ^= row&7 (reads 2-way max = free). Epilogue: BN partial stats.
// ---------------------------------------------------------------------------
__global__ __launch_bounds__(256, 2) void k2_gemm(const unsigned short* __restrict__ AX,
                                                  const unsigned short* __restrict__ WC,
                                                  float* __restrict__ out,
                                                  float* __restrict__ sums) {
  __shared__ unsigned short As[2][128 * 64];   // 16 KB each
  __shared__ unsigned short Bs[2][64 * 64];    // 8 KB each
  __shared__ float cs[64], cq[64];
  const int t = threadIdx.x;
  const int w = t >> 6, lane = t & 63, l15 = lane & 15, quad = lane >> 4;
  const int m0 = (blockIdx.x >> 2) * 128, n0 = (blockIdx.x & 3) * 64;
  if (t < 64) { cs[t] = 0.f; cq[t] = 0.f; }

  // DMA source offsets (element units, within a k-slab): unit u -> row u>>3,
  // slot chunk u&7 holds global chunk (u&7)^(row&7).
  int aOff[4], bOff[2];
#pragma unroll
  for (int q = 0; q < 4; ++q) {
    int u = t + q * 256, row = u >> 3, c = (u & 7) ^ (row & 7);
    aOff[q] = (m0 + row) * 512 + c * 8;
  }
#pragma unroll
  for (int q = 0; q < 2; ++q) {
    int u = t + q * 256, row = u >> 3, c = (u & 7) ^ (row & 7);
    bOff[q] = (n0 + row) * 512 + c * 8;
  }
  const int ldsA = t * 8;                       // + q*2048 (units of ushort)
  const int ldsB = t * 8;                       // + q*2048

  const f32x4 fz = {0.f, 0.f, 0.f, 0.f};
  f32x4 acc[4][2];
#pragma unroll
  for (int i = 0; i < 4; ++i) { acc[i][0] = fz; acc[i][1] = fz; }

  // prologue: stage k-slab 0 into buffer 0
#pragma unroll
  for (int q = 0; q < 4; ++q)
    async_copy16(AX + (size_t)aOff[q], &As[0][ldsA + q * 2048]);
#pragma unroll
  for (int q = 0; q < 2; ++q)
    async_copy16(WC + (size_t)bOff[q], &Bs[0][ldsB + q * 2048]);

  for (int ki = 0; ki < 8; ++ki) {
    const int cur = ki & 1;
    __syncthreads();                           // slab ki landed; prev reads done
    if (ki < 7) {                              // prefetch ki+1
      const int kk = (ki + 1) * 64;
#pragma unroll
      for (int q = 0; q < 4; ++q)
        async_copy16(AX + (size_t)(aOff[q] + kk), &As[cur ^ 1][ldsA + q * 2048]);
#pragma unroll
      for (int q = 0; q < 2; ++q)
        async_copy16(WC + (size_t)(bOff[q] + kk), &Bs[cur ^ 1][ldsB + q * 2048]);
    }
#pragma unroll
    for (int kc = 0; kc < 2; ++kc) {
      const int c = kc * 4 + quad;
      const int rb0 = (w >> 1) * 32 + l15, rb1 = rb0 + 16;
      bf16x8 b0 = *(const bf16x8*)&Bs[cur][rb0 * 64 + ((c ^ (rb0 & 7)) * 8)];
      bf16x8 b1 = *(const bf16x8*)&Bs[cur][rb1 * 64 + ((c ^ (rb1 & 7)) * 8)];
#pragma unroll
      for (int mt = 0; mt < 4; ++mt) {
        const int ra = (w & 1) * 64 + mt * 16 + l15;
        bf16x8 af = *(const bf16x8*)&As[cur][ra * 64 + ((c ^ (ra & 7)) * 8)];
        acc[mt][0] = MFMA16(af, b0, acc[mt][0]);
        acc[mt][1] = MFMA16(af, b1, acc[mt][1]);
      }
    }
  }
#pragma unroll
  for (int mt = 0; mt < 4; ++mt)
#pragma unroll
    for (int nt = 0; nt < 2; ++nt)
#pragma unroll
      for (int r = 0; r < 4; ++r) {
        int grow = m0 + (w & 1) * 64 + mt * 16 + quad * 4 + r;
        int gcol = n0 + (w >> 1) * 32 + nt * 16 + l15;
        out[(size_t)grow * 256 + gcol] = acc[mt][nt][r];
      }
  // ---- fused BN partial stats: sum / sumsq per column ----
#pragma unroll
  for (int nt = 0; nt < 2; ++nt) {
    float a = 0.f, b2 = 0.f;
#pragma unroll
    for (int mt = 0; mt < 4; ++mt)
#pragma unroll
      for (int r = 0; r < 4; ++r) {
        float v = acc[mt][nt][r];
        a += v; b2 += v * v;
      }
    a += __shfl_xor(a, 16);  a += __shfl_xor(a, 32);
    b2 += __shfl_xor(b2, 16); b2 += __shfl_xor(b2, 32);
    if (quad == 0) {
      int ci = (w >> 1) * 32 + nt * 16 + l15;
      atomicAdd(&cs[ci], a);
      atomicAdd(&cq[ci], b2);
    }
  }
  __syncthreads();
  if (t < 64) {
    atomicAdd(&sums[n0 + t], cs[t]);
    atomicAdd(&sums[256 + n0 + t], cq[t]);
  }
}

// ---------------------------------------------------------------------------
// k4: BatchNorm (biased var) + SELU, in place on d_out. Per-channel
// scale/shift computed once per block in LDS (256 channels, 256 threads).
// ---------------------------------------------------------------------------
__global__ __launch_bounds__(256) void k4_bn_selu(float* __restrict__ out,
                                                  const float* __restrict__ sums,
                                                  const float* __restrict__ gamma,
                                                  const float* __restrict__ beta) {
  __shared__ float sc[256], sh[256];
  const int t = threadIdx.x;
  {
    const float inv_m = 1.0f / 16384.0f;
    float mean = sums[t] * inv_m;
    float var = sums[256 + t] * inv_m - mean * mean;
    float s = rsqrtf(var + BN_EPS) * gamma[t];
    sc[t] = s;
    sh[t] = beta[t] - mean * s;
  }
  __syncthreads();
  int f = (blockIdx.x * 256 + t) * 8;
  int c = f & 255;
  float4 v0 = *(const float4*)(out + f);
  float4 v1 = *(const float4*)(out + f + 4);
  float vv[8] = {v0.x, v0.y, v0.z, v0.w, v1.x, v1.y, v1.z, v1.w};
#pragma unroll
  for (int k = 0; k < 8; ++k) {
    int ch = c + k;
    float y = vv[k] * sc[ch] + sh[ch];
    float yc = fminf(fmaxf(y, -10.f), 10.f);
    float r = (y > 0.f) ? y : (SELU_ALPHA * (expf(yc) - 1.0f));
    vv[k] = SELU_SCALE * r;
  }
  float4 o0 = {vv[0], vv[1], vv[2], vv[3]};
  float4 o1 = {vv[4], vv[5], vv[6], vv[7]};
  *(float4*)(out + f) = o0;
  *(float4*)(out + f + 4) = o1;
}

// ---------------------------------------------------------------------------
extern "C" void kernel_launch(void* const* d_in, const int* in_sizes, int n_in,
                              void* d_out, int out_size, void* d_ws, size_t ws_size,
                              hipStream_t stream) {
  const float* x     = (const float*)d_in[0];
  const float* w_map = (const float*)d_in[1];
  const float* w_att = (const float*)d_in[2];
  const float* w_res = (const float*)d_in[3];
  const float* gamma = (const float*)d_in[4];
  const float* beta  = (const float*)d_in[5];
  float* out = (float*)d_out;

  // ws layout (~24.3 MB): AX 16MB | Xt 8MB | WC 256KB | sums 2KB
  unsigned short* AX = (unsigned short*)d_ws;
  unsigned short* Xt = AX + (size_t)ROWS * 512;
  unsigned short* WC = Xt + (size_t)NB * 256 * 2048;
  float* sums = (float*)(WC + 256 * 512);

  k0_prep<<<320, 256, 0, stream>>>(x, w_att, w_res, AX, Xt, WC, sums);
  k1_attn<<<256, 512, 0, stream>>>(w_map, AX, Xt, AX);
  k2_gemm<<<512, 256, 0, stream>>>(AX, WC, out, sums);
  k4_bn_selu<<<2048, 256, 0, stream>>>(out, sums, gamma, beta);
}